// Round 1
// baseline (443.703 us; speedup 1.0000x reference)
//
#include <hip/hip_runtime.h>
#include <math.h>

// HashEncoder: 4 dense grid levels, trilinear interp, F=4 features.
// Thread t -> point p = t>>2, level l = t&3. out[(p*4+l)] as float4 = out[t].

__global__ __launch_bounds__(256) void hash_encode_kernel(
    const float* __restrict__ pos,      // (N,3) fp32
    const float4* __restrict__ tab,     // (TOTAL_PARAMS) float4 entries
    float4* __restrict__ out,           // (N*4) float4  == (N,16) floats
    int n_points,
    float s0, float s1, float s2, float s3,
    int r0, int r1, int r2, int r3,
    int o0, int o1, int o2, int o3)
{
    int t = blockIdx.x * blockDim.x + threadIdx.x;
    int p = t >> 2;
    if (p >= n_points) return;
    int l = t & 3;

    // per-lane select of level constants (cndmask chains, no scratch)
    float scale = (l == 0) ? s0 : (l == 1) ? s1 : (l == 2) ? s2 : s3;
    int   res   = (l == 0) ? r0 : (l == 1) ? r1 : (l == 2) ? r2 : r3;
    int   off   = (l == 0) ? o0 : (l == 1) ? o1 : (l == 2) ? o2 : o3;

    float px = pos[3 * p + 0];
    float py = pos[3 * p + 1];
    float pz = pos[3 * p + 2];

    float hx = px * scale + 0.5f;
    float hy = py * scale + 0.5f;
    float hz = pz * scale + 0.5f;
    float gx = floorf(hx), gy = floorf(hy), gz = floorf(hz);
    float wx = hx - gx,   wy = hy - gy,   wz = hz - gz;
    float ox = 1.0f - wx, oy = 1.0f - wy, oz = 1.0f - wz;
    int ix = (int)gx, iy = (int)gy, iz = (int)gz;

    int res2 = res * res;
    int base = off + ix + iy * res + iz * res2;

    float4 acc = make_float4(0.f, 0.f, 0.f, 0.f);
#pragma unroll
    for (int c = 0; c < 8; ++c) {
        int   idx = base + ((c & 1) ? 1 : 0) + ((c & 2) ? res : 0) + ((c & 4) ? res2 : 0);
        float w   = ((c & 1) ? wx : ox) * ((c & 2) ? wy : oy) * ((c & 4) ? wz : oz);
        float4 v  = tab[idx];
        acc.x += w * v.x;
        acc.y += w * v.y;
        acc.z += w * v.z;
        acc.w += w * v.w;
    }
    out[t] = acc;
}

extern "C" void kernel_launch(void* const* d_in, const int* in_sizes, int n_in,
                              void* d_out, int out_size, void* d_ws, size_t ws_size,
                              hipStream_t stream) {
    const float*  positions = (const float*)d_in[0];   // (N,3)
    const float4* table     = (const float4*)d_in[1];  // TOTAL_HASH_SIZE floats = TOTAL_PARAMS float4
    float4*       out       = (float4*)d_out;

    int n_points = in_sizes[0] / 3;

    // Level metadata, computed exactly as the Python reference (double precision).
    const double B_SCALE = 1.3195079565048218;
    const double BASE = 32.0;
    const long   MAX_PARAMS = 1L << 19;
    float scales[4];
    int   res[4], offs[4];
    long  off = 0;
    for (int l = 0; l < 4; ++l) {
        double s = BASE * pow(B_SCALE, (double)l) - 1.0;
        scales[l] = (float)s;
        int r = (int)ceil(s) + 1;
        res[l] = r;
        offs[l] = (int)off;
        long pcount = (long)r * r * r;
        if (pcount % 8 != 0) pcount = (pcount + 7) / 8 * 8;
        if (pcount > MAX_PARAMS) pcount = MAX_PARAMS;
        off += pcount;
    }

    long n_threads = 4L * n_points;
    int  block = 256;
    long grid = (n_threads + block - 1) / block;
    hash_encode_kernel<<<dim3((unsigned)grid), dim3(block), 0, stream>>>(
        positions, table, out, n_points,
        scales[0], scales[1], scales[2], scales[3],
        res[0], res[1], res[2], res[3],
        offs[0], offs[1], offs[2], offs[3]);
}